// Round 15
// baseline (177.821 us; speedup 1.0000x reference)
//
#include <hip/hip_runtime.h>
#include <math.h>

// HarmonicCQT via f16 MFMA: out[b,t,k] = |sum_n xpad[t*512+n] * (kr[k,n]+i*ki[k,n])|
//
// Path P2 (ws >= ~33MB), 3 dispatches, no atomics, 128-frame WGs:
//   1. prep_fused     : audio->f16 xp + B-fragment pack
//   2. cqt_mfma128    : async-DMA double-buffered K-loop, wave tile =
//        128 frames x 16 bins (B staged bytes amortized 4x vs R13: total
//        staged 760->332 MB against the measured 16.2 TB/s = 63 B/cyc/CU
//        LDS-fill ceiling). Stage = 1 chunk (16 KB), dbuf 32 KB LDS,
//        768 WGs (~3/CU). f16 partial stores (R14-verified).
//   3. cqt_mag_part128: sum <=26 slice partials (coalesced) -> magnitude
// Path P (ws >= ~14.95MB): R14 32-frame partial path (total ~122us).
// Path A (ws >= ~10.8MB): R13 atomic path (total ~128us).
// Path B (ws >= ~7.7MB): round-3 LDS-staging MFMA kernel (~224us).
// Path C: verified fp32 kernel (~370us).
//
// MFMA 16x16x32 layouts (verified rounds 3-14, absmax 4.9e-4):
//   A[m=lane&15][k=(lane>>4)*8+j], B[k=(lane>>4)*8+j][n=lane&15],
//   C/D: col=lane&15, row=(lane>>4)*4+reg.
// bp layout per 16-bin chunk (32 K-cols): 2048B = [64 lanes x 16B re][64 x 16B im]
// global_load_lds: per-lane GLOBAL gather ok; LDS side wave-uniform base,
// lane l lands at base + l*16 (guide m97/m104/m108; cross-wave A-staging
// with this lane rule verified R13).

namespace {
constexpr int kSR    = 22050;
constexpr int kHop   = 512;
constexpr int kBins  = 168;
constexpr int kT     = 689;
constexpr int kB     = 4;
constexpr int kS     = 352768;
constexpr float kKScale    = 4096.0f;
constexpr float kKScaleInv = 1.0f / 4096.0f;
constexpr int kG16 = 11;              // 16-bin groups (g10 = bins 160..167)
constexpr int kFBB = 88;              // path P: fb(22) * b(4)
constexpr int kFBB2 = 24;             // path P2: fb(6, 128 frames) * b(4)
constexpr int kAcc = kB * kT * kBins * 2;   // path-A split-K accumulator
constexpr int kMaxSl = 40;
// path B layout
constexpr int kTPadB   = 768;
constexpr int kBinPadB = 176;
constexpr int kAccB    = kB * kTPadB * kBinPadB * 2;
}

typedef _Float16 half8 __attribute__((ext_vector_type(8)));
typedef _Float16 half2v __attribute__((ext_vector_type(2)));
typedef float floatx4 __attribute__((ext_vector_type(4)));

struct Jobs {          // path B job table
  int k0[48];
  int lo[48];
  int hi[48];
  int n;
};

struct JobsC {         // path P2/P/A tables
  int lo16[kG16];      // support start col per 16-bin group (256-aligned)
  int cb16[kG16];      // chunk-prefix per group (bp indexing)
  int mlo[3];          // macro-group (64-bin) support start col
  int sm[kMaxSl];      // per slice: macro id
  int slo[kMaxSl];     // per slice: chunk range [slo,shi) rel. to mlo
  int shi[kMaxSl];
  int sbeg[3];         // first slice index of macro
  int scnt[3];         // slice count of macro
  int ns;
  int totch;
};

__device__ inline void atomAddF(float* p, float v) {
  __hip_atomic_fetch_add(p, v, __ATOMIC_RELAXED, __HIP_MEMORY_SCOPE_AGENT);
}

typedef __attribute__((address_space(3))) unsigned int lds_uint;
typedef __attribute__((address_space(1))) const unsigned int glb_uint;
__device__ __forceinline__ void dma16(const void* g, void* l) {
  __builtin_amdgcn_global_load_lds((glb_uint*)g, (lds_uint*)l, 16, 0, 0);
}

// ---- fused prep: [0,nbx) audio | [nbx,nbx+nbp) bpack | [.., +nba) zero acc ----
__global__ __launch_bounds__(256) void prep_fused(
    const float* __restrict__ x, const float* __restrict__ kr,
    const float* __restrict__ ki, _Float16* __restrict__ xp,
    _Float16* __restrict__ bp, float* __restrict__ accb,
    const int pad, const int xps, const int nmax,
    const int nbx, const int nbp, const JobsC jt) {
  int bid = blockIdx.x;
  const int tid = threadIdx.x;

  if (bid < nbx) {
    const int octx = xps >> 3;
    const int gid = bid * 256 + tid;
    if (gid >= kB * octx) return;
    const int b = gid / octx;
    const int i = (gid - b * octx) * 8;
    const float* xb = x + (size_t)b * kS - pad;
    half8 h;
    #pragma unroll
    for (int j = 0; j < 8; ++j) {
      const int e = i + j;
      h[j] = (e >= pad && e < pad + kS) ? (_Float16)xb[e] : (_Float16)0.f;
    }
    *(half8*)&xp[(size_t)b * xps + i] = h;
    return;
  }
  bid -= nbx;

  if (bid < nbp) {
    const int chunkid = bid * 4 + (tid >> 6);
    const int lane = tid & 63;
    if (chunkid >= jt.totch) return;
    int g = 0;
    #pragma unroll
    for (int j = 1; j < kG16; ++j)
      if (chunkid >= jt.cb16[j]) g = j;
    const int c = chunkid - jt.cb16[g];
    const int mm = lane & 15;
    const int q  = lane >> 4;
    const int bin  = g * 16 + mm;
    const int col0 = jt.lo16[g] + c * 32 + q * 8;
    const bool binok = (bin < kBins);
    const float* rowr = kr + (size_t)bin * nmax;
    const float* rowi = ki + (size_t)bin * nmax;
    half8 hre, him;
    #pragma unroll
    for (int j = 0; j < 8; ++j) {
      const int col = col0 + j;
      const bool ok = binok && (col < nmax);
      hre[j] = ok ? (_Float16)(rowr[col] * kKScale) : (_Float16)0.f;
      him[j] = ok ? (_Float16)(rowi[col] * kKScale) : (_Float16)0.f;
    }
    _Float16* dst = bp + (size_t)chunkid * 1024 + lane * 8;
    *(half8*)dst = hre;
    *(half8*)(dst + 512) = him;
    return;
  }
  bid -= nbp;

  const int idx = (bid * 256 + tid) * 4;
  if (idx < kAcc)
    *(floatx4*)&accb[idx] = (floatx4){0.f, 0.f, 0.f, 0.f};
}

// ---- path P2 main: 128-frame wave tiles, 1-chunk stages, partial stores ----
// LDS per buffer (halfs): A [tl(8)] x 512 at 0..4095;
//                         B [wave(4)][re/im] x 512 at 4096..8191.
__global__ __launch_bounds__(256) void cqt_mfma128(
    const _Float16* __restrict__ bp, const _Float16* __restrict__ xp,
    _Float16* __restrict__ part, const int xps, const JobsC jt) {
  __shared__ _Float16 lds[2][8192];   // 2 x 16 KB

  const int sx  = blockIdx.y;
  const int fbb = blockIdx.x;          // 0..23
  const int fb  = fbb >> 2;            // 0..5 (128 frames each)
  const int b   = fbb & 3;
  const int tid  = threadIdx.x;
  const int wave = tid >> 6;
  const int lane = tid & 63;
  const int mm = lane & 15;
  const int q  = lane >> 4;
  const int mac = jt.sm[sx];
  const int g16 = mac * 4 + wave;
  const bool gvalid = (g16 < kG16);
  const int mlo = jt.mlo[mac];
  const int gs = gvalid ? ((jt.lo16[g16] - mlo) >> 5) : 0x7fffffff;
  const int slo = jt.slo[sx];
  const int shi = jt.shi[sx];
  const int fbase = fb * 128;

  // A-DMA: wave w stages tl = w and tl = w+4 (1 KB each); lane l -> base+l*16
  const _Float16* xb = xp + (size_t)b * xps;
  int aoff[2];
  #pragma unroll
  for (int j = 0; j < 2; ++j) {
    const int tl = wave + j * 4;
    int row = fbase + tl * 16 + mm;
    if (row > kT - 1) row = kT - 1;   // dup data; discarded by t-guard later
    aoff[j] = row * kHop + q * 8;
  }
  const _Float16* bgrp =
      gvalid ? (bp + (size_t)(jt.cb16[g16] - gs) * 1024 + lane * 8) : bp;

  floatx4 accr[8], acci[8];
  #pragma unroll
  for (int tl = 0; tl < 8; ++tl) {
    accr[tl] = (floatx4){0.f, 0.f, 0.f, 0.f};
    acci[tl] = (floatx4){0.f, 0.f, 0.f, 0.f};
  }

  auto stageDMA = [&](int c, int buf) {
    _Float16* L = lds[buf];
    #pragma unroll
    for (int j = 0; j < 2; ++j)
      dma16(xb + mlo + c * 32 + aoff[j], L + (wave + j * 4) * 512);
    if (gvalid && c >= gs) {          // wave-uniform condition
      const _Float16* bs = bgrp + (size_t)c * 1024;
      dma16(bs,       L + 4096 + wave * 1024);
      dma16(bs + 512, L + 4096 + wave * 1024 + 512);
    }
  };

  auto compute = [&](int c, int buf) {
    if (!gvalid || c < gs) return;
    const _Float16* L = lds[buf];
    const half8 Bre = *(const half8*)(L + 4096 + wave * 1024 + lane * 8);
    const half8 Bim = *(const half8*)(L + 4096 + wave * 1024 + 512 + lane * 8);
    #pragma unroll
    for (int tl = 0; tl < 8; ++tl) {
      const half8 A = *(const half8*)(L + tl * 512 + lane * 8);
      accr[tl] = __builtin_amdgcn_mfma_f32_16x16x32_f16(A, Bre, accr[tl], 0, 0, 0);
      acci[tl] = __builtin_amdgcn_mfma_f32_16x16x32_f16(A, Bim, acci[tl], 0, 0, 0);
    }
  };

  // 2-barrier double-buffered pipeline (m97 structure, verified R9-R14)
  stageDMA(slo, 0);
  int buf = 0;
  #pragma unroll 1
  for (int c = slo; c < shi; ++c) {
    __syncthreads();                   // drains this stage's DMA (vmcnt)
    if (c + 1 < shi) stageDMA(c + 1, buf ^ 1);
    compute(c, buf);
    buf ^= 1;
  }

  // epilogue: f16 partial stores, layout [tl][lane][8] (coalesced per tl)
  _Float16* pw = part +
      (((size_t)sx * kFBB2 + fbb) * 4 + wave) * 4096 + lane * 8;
  #pragma unroll
  for (int tl = 0; tl < 8; ++tl) {
    half8 p;
    #pragma unroll
    for (int r = 0; r < 4; ++r) {
      p[r * 2]     = (_Float16)accr[tl][r];
      p[r * 2 + 1] = (_Float16)acci[tl][r];
    }
    *(half8*)(pw + tl * 512) = p;
  }
}

// ---- path P2 final: sum slice partials -> magnitude -> out ----
__global__ __launch_bounds__(256) void cqt_mag_part128(
    const _Float16* __restrict__ part, float* __restrict__ out,
    const JobsC jt) {
  const int fbb = blockIdx.x;          // 0..23
  const int fb = fbb >> 2;
  const int b  = fbb & 3;
  const int wave = threadIdx.x >> 6;
  const int lane = threadIdx.x & 63;
  const int g16 = blockIdx.y * 4 + wave;
  if (g16 >= kG16) return;
  const int mac = g16 >> 2;
  const int w   = g16 & 3;
  const int mm = lane & 15;
  const int q  = lane >> 4;

  float a[8][8];
  #pragma unroll
  for (int tl = 0; tl < 8; ++tl)
    #pragma unroll
    for (int j = 0; j < 8; ++j) a[tl][j] = 0.f;

  const int s0 = jt.sbeg[mac];
  const int s1 = s0 + jt.scnt[mac];
  #pragma unroll 1
  for (int s = s0; s < s1; ++s) {
    const _Float16* p = part +
        (((size_t)s * kFBB2 + fbb) * 4 + w) * 4096 + lane * 8;
    #pragma unroll
    for (int tl = 0; tl < 8; ++tl) {
      const half8 v = *(const half8*)(p + tl * 512);
      #pragma unroll
      for (int j = 0; j < 8; ++j) a[tl][j] += (float)v[j];
    }
  }
  const int k = g16 * 16 + mm;
  if (k >= kBins) return;
  #pragma unroll
  for (int tl = 0; tl < 8; ++tl) {
    #pragma unroll
    for (int r = 0; r < 4; ++r) {
      const int t = fb * 128 + tl * 16 + q * 4 + r;
      if (t < kT) {
        const float re = a[tl][r * 2];
        const float im = a[tl][r * 2 + 1];
        out[((size_t)b * kT + t) * kBins + k] =
            sqrtf(re * re + im * im) * kKScaleInv;
      }
    }
  }
}

// ---- path P/A main: 32-frame WGs (R13/R14-verified) ----
template <bool PARTIAL>
__global__ __launch_bounds__(256) void cqt_mfma_t(
    const _Float16* __restrict__ bp, const _Float16* __restrict__ xp,
    float* __restrict__ accb, _Float16* __restrict__ part,
    const int xps, const JobsC jt) {
  __shared__ _Float16 lds[2][10240];   // 2 x 20 KB

  const int sx = blockIdx.y;
  const int fb = blockIdx.x >> 2;      // 0..21 (32 frames each)
  const int b  = blockIdx.x & 3;
  const int tid  = threadIdx.x;
  const int wave = tid >> 6;
  const int lane = tid & 63;
  const int mm = lane & 15;
  const int q  = lane >> 4;
  const int mac = jt.sm[sx];
  const int g16 = mac * 4 + wave;
  const bool gvalid = (g16 < kG16);
  const int mlo = jt.mlo[mac];
  const int gs = gvalid ? ((jt.lo16[g16] - mlo) >> 5) : 0x7fffffff;
  const int slo = jt.slo[sx];
  const int shi = jt.shi[sx];
  const int fbase = fb * 32;

  const _Float16* xb = xp + (size_t)b * xps;
  int aoff;
  {
    const int tl = wave & 1;
    int row = fbase + tl * 16 + mm;
    if (row > kT - 1) row = kT - 1;
    aoff = row * kHop + q * 8 + ((wave >> 1) * 32);
  }
  const _Float16* bgrp =
      gvalid ? (bp + (size_t)(jt.cb16[g16] - gs) * 1024 + lane * 8) : bp;

  floatx4 accr[2], acci[2];
  #pragma unroll
  for (int tl = 0; tl < 2; ++tl) {
    accr[tl] = (floatx4){0.f, 0.f, 0.f, 0.f};
    acci[tl] = (floatx4){0.f, 0.f, 0.f, 0.f};
  }

  auto stageDMA = [&](int c, int buf) {
    _Float16* L = lds[buf];
    dma16(xb + mlo + c * 32 + aoff, L + wave * 512);
    if (gvalid && c >= gs) {
      const _Float16* bs = bgrp + (size_t)c * 1024;
      #pragma unroll
      for (int cc = 0; cc < 2; ++cc)
        #pragma unroll
        for (int ri = 0; ri < 2; ++ri)
          dma16(bs + cc * 1024 + ri * 512,
                L + 2048 + (wave * 4 + cc * 2 + ri) * 512);
    }
  };

  auto compute = [&](int c, int buf) {
    if (!gvalid || c < gs) return;
    const _Float16* L = lds[buf];
    #pragma unroll
    for (int cc = 0; cc < 2; ++cc) {
      const half8 Bre = *(const half8*)(L + 2048 + (wave * 4 + cc * 2) * 512 + lane * 8);
      const half8 Bim = *(const half8*)(L + 2048 + (wave * 4 + cc * 2 + 1) * 512 + lane * 8);
      #pragma unroll
      for (int tl = 0; tl < 2; ++tl) {
        const half8 A = *(const half8*)(L + (cc * 2 + tl) * 512 + lane * 8);
        accr[tl] = __builtin_amdgcn_mfma_f32_16x16x32_f16(A, Bre, accr[tl], 0, 0, 0);
        acci[tl] = __builtin_amdgcn_mfma_f32_16x16x32_f16(A, Bim, acci[tl], 0, 0, 0);
      }
    }
  };

  stageDMA(slo, 0);
  int buf = 0;
  #pragma unroll 1
  for (int c = slo; c < shi; c += 2) {
    __syncthreads();
    if (c + 2 < shi) stageDMA(c + 2, buf ^ 1);
    compute(c, buf);
    buf ^= 1;
  }

  if (PARTIAL) {
    _Float16* pw = part +
        (((size_t)sx * kFBB + blockIdx.x) * 4 + wave) * 1024 + lane * 16;
    half8 p0, p1;
    #pragma unroll
    for (int r = 0; r < 4; ++r) {
      p0[r * 2]     = (_Float16)accr[0][r];
      p0[r * 2 + 1] = (_Float16)acci[0][r];
      p1[r * 2]     = (_Float16)accr[1][r];
      p1[r * 2 + 1] = (_Float16)acci[1][r];
    }
    *(half8*)pw = p0;
    *(half8*)(pw + 8) = p1;
  } else {
    const int bin = g16 * 16 + mm;
    if (bin < kBins) {
      #pragma unroll
      for (int tl = 0; tl < 2; ++tl) {
        const int tb = fbase + tl * 16 + q * 4;
        #pragma unroll
        for (int r = 0; r < 4; ++r) {
          const int t = tb + r;
          if (t < kT) {
            const size_t o = (((size_t)b * kT + t) * kBins + bin) * 2;
            atomAddF(&accb[o],     accr[tl][r] * kKScaleInv);
            atomAddF(&accb[o + 1], acci[tl][r] * kKScaleInv);
          }
        }
      }
    }
  }
}

// ---- path P final: sum slice partials -> magnitude -> out (32-frame) ----
__global__ __launch_bounds__(256) void cqt_mag_part(
    const _Float16* __restrict__ part, float* __restrict__ out,
    const JobsC jt) {
  const int fbb = blockIdx.x;          // 0..87
  const int fb = fbb >> 2;
  const int b  = fbb & 3;
  const int wave = threadIdx.x >> 6;
  const int lane = threadIdx.x & 63;
  const int g16 = blockIdx.y * 4 + wave;
  if (g16 >= kG16) return;
  const int mac = g16 >> 2;
  const int w   = g16 & 3;
  const int mm = lane & 15;
  const int q  = lane >> 4;

  float a[16];
  #pragma unroll
  for (int i = 0; i < 16; ++i) a[i] = 0.f;
  const int s0 = jt.sbeg[mac];
  const int s1 = s0 + jt.scnt[mac];
  #pragma unroll 1
  for (int s = s0; s < s1; ++s) {
    const _Float16* p = part +
        (((size_t)s * kFBB + fbb) * 4 + w) * 1024 + lane * 16;
    const half8 v0 = *(const half8*)p;
    const half8 v1 = *(const half8*)(p + 8);
    #pragma unroll
    for (int j = 0; j < 8; ++j) {
      a[j]     += (float)v0[j];
      a[8 + j] += (float)v1[j];
    }
  }
  const int k = g16 * 16 + mm;
  if (k >= kBins) return;
  #pragma unroll
  for (int tl = 0; tl < 2; ++tl) {
    #pragma unroll
    for (int r = 0; r < 4; ++r) {
      const int t = fb * 32 + tl * 16 + q * 4 + r;
      if (t < kT) {
        const float re = a[tl * 8 + r * 2];
        const float im = a[tl * 8 + r * 2 + 1];
        out[((size_t)b * kT + t) * kBins + k] =
            sqrtf(re * re + im * im) * kKScaleInv;
      }
    }
  }
}

// ---- path A final: magnitude, 4 outputs/thread ----
__global__ __launch_bounds__(256) void cqt_mag4(
    const float* __restrict__ accb, float* __restrict__ out) {
  const int gid = (blockIdx.x * 256 + threadIdx.x) * 4;
  if (gid >= kB * kT * kBins) return;
  const floatx4 v0 = *(const floatx4*)&accb[gid * 2];
  const floatx4 v1 = *(const floatx4*)&accb[gid * 2 + 4];
  floatx4 o;
  o[0] = sqrtf(v0[0] * v0[0] + v0[1] * v0[1]);
  o[1] = sqrtf(v0[2] * v0[2] + v0[3] * v0[3]);
  o[2] = sqrtf(v1[0] * v1[0] + v1[1] * v1[1]);
  o[3] = sqrtf(v1[2] * v1[2] + v1[3] * v1[3]);
  *(floatx4*)&out[gid] = o;
}

// ---- path B final: magnitude (layout-parametric) ----
__global__ __launch_bounds__(256) void cqt_mag_final(
    const float* __restrict__ accb, float* __restrict__ out,
    const int tp, const int kp) {
  int gid = blockIdx.x * 256 + threadIdx.x;
  if (gid >= kB * kT * kBins) return;
  const int k = gid % kBins;
  const int r = gid / kBins;
  const int t = r % kT;
  const int b = r / kT;
  const float2 v = ((const float2*)accb)[((size_t)b * tp + t) * kp + k];
  out[gid] = sqrtf(v.x * v.x + v.y * v.y);
}

// ================= path B: round-3 LDS-staging MFMA (verified) =============
__global__ __launch_bounds__(256) void prep_x_kernel(
    const float* __restrict__ x, _Float16* __restrict__ xp,
    const int pad, const int xps) {
  const int halfx = xps >> 1;
  int gid = blockIdx.x * 256 + threadIdx.x;
  if (gid >= kB * halfx) return;
  const int b = gid / halfx;
  const int i = (gid - b * halfx) * 2;
  float v0 = 0.f, v1 = 0.f;
  if (i     >= pad && i     < pad + kS) v0 = x[(size_t)b * kS + (i - pad)];
  if (i + 1 >= pad && i + 1 < pad + kS) v1 = x[(size_t)b * kS + (i + 1 - pad)];
  half2v h; h.x = (_Float16)v0; h.y = (_Float16)v1;
  *(half2v*)&xp[(size_t)b * xps + i] = h;
}

__global__ __launch_bounds__(256) void cqt_mfma_kernel(
    const float* __restrict__ kr, const float* __restrict__ ki,
    const _Float16* __restrict__ xp, float* __restrict__ accb,
    const int nmax, const int xps, const Jobs jt) {
  __shared__ _Float16 Bs[2][16][264];
  const int jb = blockIdx.x;
  const int k0   = jt.k0[jb];
  const int n_lo = jt.lo[jb];
  const int n_hi = jt.hi[jb];
  const int b  = blockIdx.z;
  const int fb = blockIdx.y;
  const int tid  = threadIdx.x;
  const int lane = tid & 63;
  const int wave = tid >> 6;
  const int m = lane & 15;
  const int q = lane >> 4;
  const int sbin = tid >> 4;
  const int scol = tid & 15;
  const int gbin = k0 + sbin;
  const bool binok = (gbin < kBins);
  const float* rowr = kr + (size_t)gbin * nmax;
  const float* rowi = ki + (size_t)gbin * nmax;
  const int fbase = fb * 256 + wave * 64;
  const _Float16* ax =
      xp + (size_t)b * xps + (size_t)(fbase + m) * kHop + q * 8;
  floatx4 accr[4], acci[4];
  #pragma unroll
  for (int tl = 0; tl < 4; ++tl) {
    accr[tl] = (floatx4){0.f, 0.f, 0.f, 0.f};
    acci[tl] = (floatx4){0.f, 0.f, 0.f, 0.f};
  }
  for (int n0r = n_lo; n0r < n_hi; n0r += 256) {
    __syncthreads();
    #pragma unroll
    for (int c = 0; c < 16; ++c) {
      const int col = n0r + scol + c * 16;
      const bool ok = binok && (col < nmax);
      const float vr = ok ? rowr[col] : 0.f;
      const float vi = ok ? rowi[col] : 0.f;
      Bs[0][sbin][scol + c * 16] = (_Float16)(vr * kKScale);
      Bs[1][sbin][scol + c * 16] = (_Float16)(vi * kKScale);
    }
    __syncthreads();
    const _Float16* axr = ax + n0r;
    #pragma unroll
    for (int c = 0; c < 8; ++c) {
      const int ko = c * 32 + q * 8;
      const half8 br = *(const half8*)&Bs[0][m][ko];
      const half8 bi = *(const half8*)&Bs[1][m][ko];
      #pragma unroll
      for (int tl = 0; tl < 4; ++tl) {
        const half8 a = *(const half8*)(axr + tl * 16 * kHop + c * 32);
        accr[tl] = __builtin_amdgcn_mfma_f32_16x16x32_f16(a, br, accr[tl], 0, 0, 0);
        acci[tl] = __builtin_amdgcn_mfma_f32_16x16x32_f16(a, bi, acci[tl], 0, 0, 0);
      }
    }
  }
  #pragma unroll
  for (int tl = 0; tl < 4; ++tl) {
    #pragma unroll
    for (int rr = 0; rr < 4; ++rr) {
      const int t = fbase + tl * 16 + q * 4 + rr;
      const size_t o = (((size_t)b * kTPadB + t) * kBinPadB + (k0 + m)) * 2;
      atomAddF(&accb[o],     accr[tl][rr] * kKScaleInv);
      atomAddF(&accb[o + 1], acci[tl][rr] * kKScaleInv);
    }
  }
}

// ================= path C: verified fp32 kernel (round 2) ==================
namespace fb32 {
constexpr int TT = 8;
constexpr int KG = 4;
constexpr int kTTiles  = (kT + TT - 1) / TT;
constexpr int kKGroups = kBins / KG;
constexpr int kWaves   = kB * kTTiles * kKGroups;
}

__global__ __launch_bounds__(256) void cqt_mag_kernel(
    const float* __restrict__ x,
    const float* __restrict__ kr,
    const float* __restrict__ ki,
    float* __restrict__ out,
    const int nmax, const int pad) {
  using namespace fb32;
  const int wave = (blockIdx.x << 2) + (threadIdx.x >> 6);
  const int lane = threadIdx.x & 63;
  if (wave >= kWaves) return;
  const int kg    = wave / (kB * kTTiles);
  const int rem   = wave - kg * (kB * kTTiles);
  const int b     = rem / kTTiles;
  const int ttile = rem - b * kTTiles;
  const int k0 = kg * KG;
  const int t0 = ttile * TT;
  const double Q  = 1.0 / (exp2(1.0 / 24.0) - 1.0);
  const double f0 = 32.7 * exp2((double)k0 / 24.0);
  int N = (int)ceil(Q * (double)kSR / f0) + 8;
  int full_start = nmax - N;
  if (full_start < 0) full_start = 0;
  int tbase[TT], lo[TT], t_last;
  { int t = t0 + TT - 1; if (t > kT - 1) t = kT - 1; t_last = t; }
  #pragma unroll
  for (int tt = 0; tt < TT; ++tt) {
    int t = t0 + tt; if (t > kT - 1) t = kT - 1;
    tbase[tt] = b * kS + t * kHop - pad;
    lo[tt]    = pad - t * kHop;
  }
  int head_start = pad - t_last * kHop;
  if (head_start < full_start) head_start = full_start;
  int safe = pad - t0 * kHop;
  if (safe < head_start) safe = head_start;
  int body_start = nmax - ((nmax - safe) & ~63);
  float accr[TT][KG], acci[TT][KG];
  #pragma unroll
  for (int tt = 0; tt < TT; ++tt)
    #pragma unroll
    for (int kk = 0; kk < KG; ++kk) { accr[tt][kk] = 0.f; acci[tt][kk] = 0.f; }
  for (int n = body_start - 64; n > head_start - 64; n -= 64) {
    const int nn = n + lane;
    const bool kok = (nn >= 0);
    float krv[KG], kiv[KG];
    #pragma unroll
    for (int kk = 0; kk < KG; ++kk) {
      krv[kk] = kok ? kr[(k0 + kk) * nmax + nn] : 0.f;
      kiv[kk] = kok ? ki[(k0 + kk) * nmax + nn] : 0.f;
    }
    float a[TT];
    #pragma unroll
    for (int tt = 0; tt < TT; ++tt)
      a[tt] = (nn >= lo[tt]) ? x[tbase[tt] + nn] : 0.f;
    #pragma unroll
    for (int tt = 0; tt < TT; ++tt)
      #pragma unroll
      for (int kk = 0; kk < KG; ++kk) {
        accr[tt][kk] = fmaf(a[tt], krv[kk], accr[tt][kk]);
        acci[tt][kk] = fmaf(a[tt], kiv[kk], acci[tt][kk]);
      }
  }
  for (int n = body_start; n < nmax; n += 64) {
    const int nn = n + lane;
    float krv[KG], kiv[KG];
    #pragma unroll
    for (int kk = 0; kk < KG; ++kk) {
      krv[kk] = kr[(k0 + kk) * nmax + nn];
      kiv[kk] = ki[(k0 + kk) * nmax + nn];
    }
    float a[TT];
    #pragma unroll
    for (int tt = 0; tt < TT; ++tt)
      a[tt] = x[tbase[tt] + nn];
    #pragma unroll
    for (int tt = 0; tt < TT; ++tt)
      #pragma unroll
      for (int kk = 0; kk < KG; ++kk) {
        accr[tt][kk] = fmaf(a[tt], krv[kk], accr[tt][kk]);
        acci[tt][kk] = fmaf(a[tt], kiv[kk], acci[tt][kk]);
      }
  }
  #pragma unroll
  for (int tt = 0; tt < TT; ++tt) {
    #pragma unroll
    for (int kk = 0; kk < KG; ++kk) {
      float r = accr[tt][kk];
      float i = acci[tt][kk];
      #pragma unroll
      for (int s = 32; s > 0; s >>= 1) {
        r += __shfl_xor(r, s, 64);
        i += __shfl_xor(i, s, 64);
      }
      if (lane == 0) {
        const int t = t0 + tt;
        if (t < kT)
          out[(b * kT + t) * kBins + (k0 + kk)] = sqrtf(r * r + i * i);
      }
    }
  }
}
// ============================================================================

extern "C" void kernel_launch(void* const* d_in, const int* in_sizes, int n_in,
                              void* d_out, int out_size, void* d_ws, size_t ws_size,
                              hipStream_t stream) {
  const float* x  = (const float*)d_in[0];   // [4, 1, 352768]
  const float* kr = (const float*)d_in[1];   // [168, nmax]
  const float* ki = (const float*)d_in[2];   // [168, nmax]
  float* out = (float*)d_out;                // [4, 1, 689, 168]

  const int nmax = in_sizes[1] / kBins;      // 23013 (runtime truth)
  const int pad  = nmax - kHop;

  const int kcap = ((nmax + 255) / 256) * 256;   // 23040
  const double Q = 1.0 / (exp2(1.0 / 24.0) - 1.0);

  // ---- common group table ----
  JobsC jc;
  int tot = 0;
  for (int g = 0; g < kG16; ++g) {
    const double f0 = 32.7 * exp2((double)(16 * g) / 24.0);
    const int N = (int)ceil(Q * (double)kSR / f0) + 8;
    int lo = nmax - N;
    if (lo < 0) lo = 0;
    lo &= ~255;
    jc.lo16[g] = lo;
    jc.cb16[g] = tot;
    tot += (kcap - lo) / 32;
  }
  jc.totch = tot;                        // ~1980 chunks
  for (int m = 0; m < 3; ++m) jc.mlo[m] = jc.lo16[4 * m];

  // slice builder: target max slice length `maxlen` chunks, align `al`
  auto build_slices = [&](JobsC& j, int maxlen, int al) {
    int ns = 0;
    for (int m = 0; m < 3; ++m) {
      j.sbeg[m] = ns;
      const int C = (kcap - j.mlo[m]) / 32;
      const int nsl = (C + maxlen - 1) / maxlen;
      const int len = (((C + nsl - 1) / nsl) + al - 1) & ~(al - 1);
      for (int s = 0; s < nsl && ns < kMaxSl; ++s) {
        const int lo = s * len;
        if (lo >= C) break;
        int hi = lo + len;
        if (hi > C) hi = C;
        j.sm[ns] = m; j.slo[ns] = lo; j.shi[ns] = hi;
        ++ns;
      }
      j.scnt[m] = ns - j.sbeg[m];
    }
    j.ns = ns;
  };

  // ---- shared ws pieces ----
  const int xpsA = (kT - 1) * kHop + kcap + 256;           // 375,552 (%8==0)
  const size_t xp_bytes = (size_t)kB * xpsA * sizeof(_Float16);
  const size_t bp_bytes = (size_t)tot * 2048;

  // path P2: xp | part2(f16) | bp   (ns=32, 128-frame)
  JobsC jc2 = jc;
  build_slices(jc2, 28, 1);            // ns ~ 26+5+1 = 32
  const size_t part2_off   = (xp_bytes + 511) & ~(size_t)511;
  const size_t part2_bytes = (size_t)jc2.ns * kFBB2 * 4 * 4096 * sizeof(_Float16);
  const size_t bp2_off     = (part2_off + part2_bytes + 511) & ~(size_t)511;
  const size_t ws_P2 = bp2_off + bp_bytes;                 // ~33 MB

  // path P: xp | part(f16) | bp   (ns=11, 32-frame)
  JobsC jcP = jc;
  build_slices(jcP, 96, 2);            // ns = 8+2+1 = 11
  const size_t partP_off   = (xp_bytes + 511) & ~(size_t)511;
  const size_t partP_bytes = (size_t)jcP.ns * kFBB * 4 * 1024 * sizeof(_Float16);
  const size_t bpP_off     = (partP_off + partP_bytes + 511) & ~(size_t)511;
  const size_t ws_P = bpP_off + bp_bytes;                  // ~14.95 MB

  // path A: xp | acc(f32) | bp
  const size_t accA_off  = (xp_bytes + 511) & ~(size_t)511;
  const size_t accA_bytes = (size_t)kAcc * sizeof(float);
  const size_t bpA_off   = (accA_off + accA_bytes + 511) & ~(size_t)511;
  const size_t ws_A = bpA_off + bp_bytes;                  // ~10.8 MB

  // path B layout
  const int xpsB = (kTPadB - 1) * kHop + kcap + 256;
  const size_t xpB_bytes = (size_t)kB * xpsB * sizeof(_Float16);
  const size_t accB_off  = (xpB_bytes + 511) & ~(size_t)511;
  const size_t accB_bytes = (size_t)kAccB * sizeof(float);
  const size_t ws_B = accB_off + accB_bytes;

  const int nbx = (kB * (xpsA / 8) + 255) / 256;   // audio blocks (8 el/thr)
  const int nbp = (tot + 3) / 4;                   // bpack blocks

  if (ws_size >= ws_P2) {
    // ---- path P2: 128-frame, partial stores ----
    _Float16* xp   = (_Float16*)d_ws;
    _Float16* part = (_Float16*)((char*)d_ws + part2_off);
    _Float16* bp   = (_Float16*)((char*)d_ws + bp2_off);

    prep_fused<<<nbx + nbp, 256, 0, stream>>>(
        x, kr, ki, xp, bp, (float*)part /*unused*/, pad, xpsA, nmax,
        nbx, nbp, jc2);
    {
      dim3 grid(kFBB2, jc2.ns);    // (24, ~32) = 768 WGs
      cqt_mfma128<<<grid, 256, 0, stream>>>(bp, xp, part, xpsA, jc2);
    }
    {
      dim3 grid(kFBB2, 3);
      cqt_mag_part128<<<grid, 256, 0, stream>>>(part, out, jc2);
    }
    return;
  }

  if (ws_size >= ws_P) {
    // ---- path P: R14 verified (total ~122us) ----
    _Float16* xp   = (_Float16*)d_ws;
    _Float16* part = (_Float16*)((char*)d_ws + partP_off);
    _Float16* bp   = (_Float16*)((char*)d_ws + bpP_off);

    prep_fused<<<nbx + nbp, 256, 0, stream>>>(
        x, kr, ki, xp, bp, (float*)part /*unused*/, pad, xpsA, nmax,
        nbx, nbp, jcP);
    {
      dim3 grid(kFBB, jcP.ns);
      cqt_mfma_t<true><<<grid, 256, 0, stream>>>(
          bp, xp, nullptr, part, xpsA, jcP);
    }
    {
      dim3 grid(kFBB, 3);
      cqt_mag_part<<<grid, 256, 0, stream>>>(part, out, jcP);
    }
    return;
  }

  if (ws_size >= ws_A) {
    // ---- path A: atomic split-K (verified ~128us) ----
    _Float16* xp = (_Float16*)d_ws;
    float* accb  = (float*)((char*)d_ws + accA_off);
    _Float16* bp = (_Float16*)((char*)d_ws + bpA_off);

    const int nba = (kAcc / 4 + 255) / 256;
    prep_fused<<<nbx + nbp + nba, 256, 0, stream>>>(
        x, kr, ki, xp, bp, accb, pad, xpsA, nmax, nbx, nbp, jcP);
    {
      dim3 grid(kFBB, jcP.ns);
      cqt_mfma_t<false><<<grid, 256, 0, stream>>>(
          bp, xp, accb, nullptr, xpsA, jcP);
    }
    {
      const int total = kB * kT * kBins;
      cqt_mag4<<<(total / 4 + 255) / 256, 256, 0, stream>>>(accb, out);
    }
    return;
  }

  if (ws_size >= ws_B) {
    // ---- path B (round-3, verified ~224us) ----
    _Float16* xp = (_Float16*)d_ws;
    float* accb  = (float*)((char*)d_ws + accB_off);
    Jobs jt;
    int nj = 0;
    for (int g = 0; g < 11; ++g) {
      const int gk0 = 16 * g;
      const double f0 = 32.7 * exp2((double)gk0 / 24.0);
      const int N = (int)ceil(Q * (double)kSR / f0) + 8;
      int lo = nmax - N;
      if (lo < 0) lo = 0;
      lo = (lo / 2048) * 2048;
      for (int s = lo; s < kcap && nj < 48; s += 2048) {
        jt.k0[nj] = gk0;
        jt.lo[nj] = s;
        jt.hi[nj] = (s + 2048 < kcap) ? s + 2048 : kcap;
        ++nj;
      }
    }
    jt.n = nj;
    hipMemsetAsync(accb, 0, accB_bytes, stream);
    {
      const int total = kB * (xpsB / 2);
      prep_x_kernel<<<(total + 255) / 256, 256, 0, stream>>>(x, xp, pad, xpsB);
    }
    {
      dim3 grid(nj, kTPadB / 256, kB);
      cqt_mfma_kernel<<<grid, 256, 0, stream>>>(kr, ki, xp, accb, nmax, xpsB, jt);
    }
    {
      const int total = kB * kT * kBins;
      cqt_mag_final<<<(total + 255) / 256, 256, 0, stream>>>(
          accb, out, kTPadB, kBinPadB);
    }
    return;
  }

  // ---- path C: fp32 fallback ----
  {
    const int blocks = fb32::kWaves / 4;
    cqt_mag_kernel<<<blocks, 256, 0, stream>>>(x, kr, ki, out, nmax, pad);
  }
}